// Round 9
// baseline (3846.423 us; speedup 1.0000x reference)
//
#include <hip/hip_runtime.h>

#define N_ATOMS 21
#define DPAIR 210      // 21*20/2
#define X3 63          // 3*N_ATOMS
#define MT 16          // m-tile per block iteration
#define NCHUNK 12      // m-chunks: 12*64=768 blocks = exactly 3/CU (VGPR-capped), all resident

__device__ __forceinline__ int pair_idx(int a, int o) {
    int hi = a > o ? a : o;
    int lo = a > o ? o : a;
    return hi * (hi - 1) / 2 + lo;
}

// ---------------- kernel 1: per-batch pair geometry ----------------
__global__ void geom_kernel(const float* __restrict__ r,
                            float* __restrict__ xs_ws, float* __restrict__ xs3_ws,
                            float* __restrict__ xs5_ws, float* __restrict__ dkl_ws,
                            float* __restrict__ c3_ws) {
    int b = blockIdx.x;
    int tid = threadIdx.x;
    __shared__ float rs[X3];
    if (tid < X3) rs[tid] = r[b * X3 + tid];
    __syncthreads();
    if (tid < DPAIR) {
        int i = (int)((1.0f + sqrtf(1.0f + 8.0f * (float)tid)) * 0.5f);
        while (i * (i - 1) / 2 > tid) --i;
        while ((i + 1) * i / 2 <= tid) ++i;
        int j = tid - i * (i - 1) / 2;   // i > j
        float dx = rs[3 * i + 0] - rs[3 * j + 0];
        float dy = rs[3 * i + 1] - rs[3 * j + 1];
        float dz = rs[3 * i + 2] - rs[3 * j + 2];
        float n2 = dx * dx + dy * dy + dz * dz;
        float inv = 1.0f / sqrtf(n2);      // xs
        float inv2 = inv * inv;
        float x3 = inv2 * inv;
        float x5 = x3 * inv2;
        int gidx = b * DPAIR + tid;
        xs_ws[gidx] = inv;
        xs3_ws[gidx] = x3;
        xs5_ws[gidx] = x5;
        dkl_ws[gidx * 3 + 0] = dx;
        dkl_ws[gidx * 3 + 1] = dy;
        dkl_ws[gidx * 3 + 2] = dz;
        c3_ws[gidx * 3 + 0] = -x3 * dx;   // contrib = -xs^3 * dkl
        c3_ws[gidx * 3 + 1] = -x3 * dy;
        c3_ws[gidx * 3 + 2] = -x3 * dz;
    }
}

// ---------------- kernel 2: main m-loop ----------------
// grid = (NCHUNK, B), 256 threads, 3 blocks/CU (VGPR ~165 no-spill; LDS 38.9KB).
// hess partial: acc[x][y] += sum_m U[m,x]*XJ[m,y] - XJ[m,x]*V[m,y]
//   with U = c1*XJ - ef*AJ, V = ef*AJ  (U/V reconstructed from XJ/AJ + scalars)
// NOTE: __launch_bounds__(256,4) forced VGPR<=128 -> scratch spill, 6.5GB fetch (round 8).
__global__ __launch_bounds__(256, 3) void main_kernel(
    const float* __restrict__ Xt, const float* __restrict__ A,
    const float* __restrict__ xs_ws, const float* __restrict__ c3_ws,
    float* __restrict__ outHess,
    float* __restrict__ gx_ws, float* __restrict__ e_ws, float* __restrict__ s2_ws,
    int Mtot)
{
    const float Q    = 0.22360679774997896f;   // sqrt(5)/SIG
    const float EFC  = 0.0008333333333333334f; // q^4/3
    const float INVQ2 = 20.0f;                 // 1/q^2

    int chunk = blockIdx.x;
    int b = blockIdx.y;
    int tid = threadIdx.x;

    __shared__ float Xt_tile[MT][DPAIR];   // 13.44 KB
    __shared__ float A_tile[MT][DPAIR];    // 13.44 KB
    __shared__ float XJ_lds[MT][64];       // 4 KB
    __shared__ float AJ_lds[MT][64];       // 4 KB
    __shared__ float xs_s[DPAIR];          // 0.84 KB
    __shared__ float c3_s[DPAIR * 3];      // 2.52 KB
    __shared__ float w1_s[MT], g_s[MT], c1_s[MT], ef_s[MT];  // 0.25 KB

    if (tid < DPAIR) xs_s[tid] = xs_ws[b * DPAIR + tid];
    for (int idx = tid; idx < DPAIR * 3; idx += 256) c3_s[idx] = c3_ws[b * DPAIR * 3 + idx];

    int MCH = (Mtot + NCHUNK - 1) / NCHUNK;
    int m0 = chunk * MCH;
    int m1 = min(Mtot, m0 + MCH);

    float acc[4][4];
    #pragma unroll
    for (int i = 0; i < 4; ++i)
        #pragma unroll
        for (int j = 0; j < 4; ++j) acc[i][j] = 0.f;
    float gxp = 0.f, e_acc = 0.f, s2_acc = 0.f;

    int tx = tid >> 4, ty = tid & 15;
    int mtg = tid >> 4, lg = tid & 15;

    for (int t0 = m0; t0 < m1; t0 += MT) {
        // ---- stage Xt/A rows: 16 consecutive m-rows contiguous -> flat float2 copy ----
        {
            int lim2 = ((Mtot - t0) * DPAIR) >> 1;             // float2 available (OOB guard)
            const float2* __restrict__ Xs = (const float2*)(Xt + (size_t)t0 * DPAIR);
            const float2* __restrict__ As = (const float2*)(A  + (size_t)t0 * DPAIR);
            float2* __restrict__ Xd = (float2*)&Xt_tile[0][0];
            float2* __restrict__ Ad = (float2*)&A_tile[0][0];
            #pragma unroll 4
            for (int idx = tid; idx < MT * DPAIR / 2; idx += 256) {
                float2 xv = make_float2(0.f, 0.f), av = make_float2(0.f, 0.f);
                if (idx < lim2) { xv = Xs[idx]; av = As[idx]; }
                Xd[idx] = xv;
                Ad[idx] = av;
            }
        }
        __syncthreads();
        // ---- per-m scalars (16 lanes per m) + private energy/S2 partials ----
        {
            float s2 = 0.f, sxa = 0.f;
            for (int d = lg; d < DPAIR; d += 16) {
                float diff = xs_s[d] - Xt_tile[mtg][d];
                s2 = fmaf(diff, diff, s2);
                sxa = fmaf(diff, A_tile[mtg][d], sxa);
            }
            for (int o = 8; o >= 1; o >>= 1) {
                s2  += __shfl_xor(s2, o, 16);
                sxa += __shfl_xor(sxa, o, 16);
            }
            if (lg == 0) {
                bool valid = (t0 + mtg) < m1;
                float dist = sqrtf(s2);
                float ef = valid ? EFC * expf(-Q * dist) : 0.f;
                float w1 = ef * (1.f + Q * dist) * INVQ2;
                float g  = ef * sxa;
                float c1v = dist > 0.f ? Q * g / dist : 0.f;
                w1_s[mtg] = w1; g_s[mtg] = g; c1_s[mtg] = c1v; ef_s[mtg] = ef;
                e_acc += w1 * sxa;   // private, per-mtg
                s2_acc += g;
            }
        }
        __syncthreads();
        // ---- grad_x partial ----
        if (tid < DPAIR) {
            #pragma unroll
            for (int mt = 0; mt < MT; ++mt)
                gxp += w1_s[mt] * A_tile[mt][tid] + g_s[mt] * Xt_tile[mt][tid];
        }
        // ---- build XJ / AJ (sparse jac application, gather per (atom,comp)) ----
        #pragma unroll
        for (int rr = 0; rr < 4; ++rr) {
            int mt = rr * 4 + (tid >> 6);
            int ac = tid & 63;
            if (ac < X3) {
                int a = ac / 3;
                int c = ac - 3 * a;
                float xjv = 0.f, ajv = 0.f;
                #pragma unroll
                for (int o = 0; o < N_ATOMS; ++o) {
                    if (o == a) continue;
                    int p = pair_idx(a, o);
                    float sgn = a > o ? 1.f : -1.f;
                    float c3v = sgn * c3_s[p * 3 + c];
                    xjv = fmaf(xs_s[p] - Xt_tile[mt][p], c3v, xjv);
                    ajv = fmaf(A_tile[mt][p], c3v, ajv);
                }
                XJ_lds[mt][ac] = xjv;
                AJ_lds[mt][ac] = ajv;
            } else {
                XJ_lds[mt][63] = 0.f; AJ_lds[mt][63] = 0.f;
            }
        }
        __syncthreads();
        // ---- 63x63 outer-product accumulation (4x4 per thread over 64x64 padded) ----
        #pragma unroll
        for (int mt = 0; mt < MT; ++mt) {
            const float4* XJ4 = (const float4*)XJ_lds[mt];
            const float4* AJ4 = (const float4*)AJ_lds[mt];
            float c1 = c1_s[mt], ef = ef_s[mt];
            float4 xr = XJ4[tx], ar = AJ4[tx], yc = XJ4[ty], av = AJ4[ty];
            float xx[4] = {xr.x, xr.y, xr.z, xr.w};
            float aa[4] = {ar.x, ar.y, ar.z, ar.w};
            float yy[4] = {yc.x, yc.y, yc.z, yc.w};
            float vv[4] = {av.x, av.y, av.z, av.w};
            float uu[4];
            #pragma unroll
            for (int i = 0; i < 4; ++i) uu[i] = c1 * xx[i] - ef * aa[i];
            #pragma unroll
            for (int j = 0; j < 4; ++j) vv[j] = ef * vv[j];
            #pragma unroll
            for (int i = 0; i < 4; ++i)
                #pragma unroll
                for (int j = 0; j < 4; ++j)
                    acc[i][j] += uu[i] * yy[j] - xx[i] * vv[j];
        }
        __syncthreads();
    }

    // ---- write partials ----
    #pragma unroll
    for (int i = 0; i < 4; ++i) {
        int x = 4 * tx + i;
        if (x >= X3) continue;
        #pragma unroll
        for (int j = 0; j < 4; ++j) {
            int y = 4 * ty + j;
            if (y >= X3) continue;
            atomicAdd(&outHess[((size_t)b * X3 + x) * X3 + y], acc[i][j]);
        }
    }
    if (tid < DPAIR) atomicAdd(&gx_ws[b * DPAIR + tid], gxp);
    if (lg == 0) { atomicAdd(&e_ws[b], e_acc); atomicAdd(&s2_ws[b], s2_acc); }
}

// ---------------- kernel 3: finalize (energy, grad, hessian corrections) ----------------
__global__ void finalize_kernel(
    const float* __restrict__ xs_ws, const float* __restrict__ xs3_ws,
    const float* __restrict__ xs5_ws, const float* __restrict__ dkl_ws,
    const float* __restrict__ c3_ws, const float* __restrict__ gx_ws,
    const float* __restrict__ e_ws, const float* __restrict__ s2_ws,
    float* __restrict__ out, int Bn)
{
    int b = blockIdx.x, tid = threadIdx.x;
    __shared__ float gx_s[DPAIR], xs3_s[DPAIR], xs5_s[DPAIR];
    __shared__ float c3s[DPAIR * 3], dkl_s[DPAIR * 3];
    float S2 = s2_ws[b];
    if (tid < DPAIR) {
        gx_s[tid]  = gx_ws[b * DPAIR + tid] - S2 * xs_ws[b * DPAIR + tid];
        xs3_s[tid] = xs3_ws[b * DPAIR + tid];
        xs5_s[tid] = xs5_ws[b * DPAIR + tid];
    }
    for (int idx = tid; idx < DPAIR * 3; idx += 256) {
        c3s[idx]   = c3_ws[b * DPAIR * 3 + idx];
        dkl_s[idx] = dkl_ws[b * DPAIR * 3 + idx];
    }
    __syncthreads();

    if (tid == 0) out[b] = e_ws[b];   // energy (STD=1, C=0)

    if (tid < X3) {  // grad[b, 3a+c] = sum over incident pairs of sign*gx[p]*c3[p][c]
        int a = tid / 3;
        int c = tid - 3 * a;
        float s = 0.f;
        #pragma unroll
        for (int o = 0; o < N_ATOMS; ++o) {
            if (o == a) continue;
            int p = pair_idx(a, o);
            float sgn = a > o ? 1.f : -1.f;
            s += sgn * gx_s[p] * c3s[p * 3 + c];
        }
        out[Bn + b * X3 + tid] = s;
    }

    float* hess = out + Bn + (size_t)Bn * X3 + (size_t)b * X3 * X3;
    for (int idx = tid; idx < X3 * X3; idx += 256) {
        int x = idx / X3, y = idx - X3 * x;
        int a1 = x / 3, ci = x - 3 * a1;
        int a2 = y / 3, cj = y - 3 * a2;
        float val = hess[idx];
        if (a1 != a2) {
            int p = pair_idx(a1, a2);
            float cc = c3s[p * 3 + ci] * c3s[p * 3 + cj];
            float ht = 3.f * gx_s[p] * xs5_s[p] * dkl_s[p * 3 + ci] * dkl_s[p * 3 + cj]
                       + (ci == cj ? -gx_s[p] * xs3_s[p] : 0.f);
            val += S2 * cc - ht;
        } else {
            int a = a1;
            #pragma unroll
            for (int o = 0; o < N_ATOMS; ++o) {
                if (o == a) continue;
                int p = pair_idx(a, o);
                float cc = c3s[p * 3 + ci] * c3s[p * 3 + cj];
                float ht = 3.f * gx_s[p] * xs5_s[p] * dkl_s[p * 3 + ci] * dkl_s[p * 3 + cj]
                           + (ci == cj ? -gx_s[p] * xs3_s[p] : 0.f);
                val += -S2 * cc + ht;
            }
        }
        hess[idx] = val;
    }
}

extern "C" void kernel_launch(void* const* d_in, const int* in_sizes, int n_in,
                              void* d_out, int out_size, void* d_ws, size_t ws_size,
                              hipStream_t stream) {
    const float* r  = (const float*)d_in[0];
    const float* Xt = (const float*)d_in[1];
    const float* A  = (const float*)d_in[2];
    int Bn   = in_sizes[0] / X3;     // 64
    int Mtot = in_sizes[1] / DPAIR;  // 6000
    float* out = (float*)d_out;

    float* ws     = (float*)d_ws;
    float* gx_ws  = ws;                               // Bn*210 (atomic, zeroed)
    float* e_ws   = gx_ws + (size_t)Bn * DPAIR;       // Bn     (atomic, zeroed)
    float* s2_ws  = e_ws + Bn;                        // Bn     (atomic, zeroed)
    float* xs_ws  = s2_ws + Bn;                       // Bn*210
    float* xs3_ws = xs_ws + (size_t)Bn * DPAIR;       // Bn*210
    float* xs5_ws = xs3_ws + (size_t)Bn * DPAIR;      // Bn*210
    float* dkl_ws = xs5_ws + (size_t)Bn * DPAIR;      // Bn*630
    float* c3_ws  = dkl_ws + (size_t)Bn * DPAIR * 3;  // Bn*630

    hipMemsetAsync(d_out, 0, (size_t)out_size * sizeof(float), stream);
    hipMemsetAsync(ws, 0, ((size_t)Bn * DPAIR + 2 * (size_t)Bn) * sizeof(float), stream);

    geom_kernel<<<Bn, 256, 0, stream>>>(r, xs_ws, xs3_ws, xs5_ws, dkl_ws, c3_ws);

    dim3 grid(NCHUNK, Bn);
    main_kernel<<<grid, 256, 0, stream>>>(Xt, A, xs_ws, c3_ws,
        out + Bn + (size_t)Bn * X3, gx_ws, e_ws, s2_ws, Mtot);

    finalize_kernel<<<Bn, 256, 0, stream>>>(xs_ws, xs3_ws, xs5_ws, dkl_ws, c3_ws,
        gx_ws, e_ws, s2_ws, out, Bn);
}

// Round 11
// 3139.424 us; speedup vs baseline: 1.2252x; 1.2252x over previous
//
#include <hip/hip_runtime.h>

#define N_ATOMS 21
#define DPAIR 210      // 21*20/2
#define X3 63          // 3*N_ATOMS
#define MT 16          // m-tile per block iteration
#define NCHUNK 8       // m-chunks: 8*64=512 blocks, all resident at 2 blocks/CU

__device__ __forceinline__ int pair_idx(int a, int o) {
    int hi = a > o ? a : o;
    int lo = a > o ? o : a;
    return hi * (hi - 1) / 2 + lo;
}

// ---------------- kernel 1: per-batch pair geometry ----------------
__global__ void geom_kernel(const float* __restrict__ r,
                            float* __restrict__ xs_ws, float* __restrict__ xs3_ws,
                            float* __restrict__ xs5_ws, float* __restrict__ dkl_ws,
                            float* __restrict__ c3_ws) {
    int b = blockIdx.x;
    int tid = threadIdx.x;
    __shared__ float rs[X3];
    if (tid < X3) rs[tid] = r[b * X3 + tid];
    __syncthreads();
    if (tid < DPAIR) {
        int i = (int)((1.0f + sqrtf(1.0f + 8.0f * (float)tid)) * 0.5f);
        while (i * (i - 1) / 2 > tid) --i;
        while ((i + 1) * i / 2 <= tid) ++i;
        int j = tid - i * (i - 1) / 2;   // i > j
        float dx = rs[3 * i + 0] - rs[3 * j + 0];
        float dy = rs[3 * i + 1] - rs[3 * j + 1];
        float dz = rs[3 * i + 2] - rs[3 * j + 2];
        float n2 = dx * dx + dy * dy + dz * dz;
        float inv = 1.0f / sqrtf(n2);      // xs
        float inv2 = inv * inv;
        float x3 = inv2 * inv;
        float x5 = x3 * inv2;
        int gidx = b * DPAIR + tid;
        xs_ws[gidx] = inv;
        xs3_ws[gidx] = x3;
        xs5_ws[gidx] = x5;
        dkl_ws[gidx * 3 + 0] = dx;
        dkl_ws[gidx * 3 + 1] = dy;
        dkl_ws[gidx * 3 + 2] = dz;
        c3_ws[gidx * 3 + 0] = -x3 * dx;   // contrib = -xs^3 * dkl
        c3_ws[gidx * 3 + 1] = -x3 * dy;
        c3_ws[gidx * 3 + 2] = -x3 * dz;
    }
}

// ---------------- kernel 2: main m-loop ----------------
// grid = (B, NCHUNK) -> b fastest-varying so co-resident blocks share an m-slab.
// NO launch_bounds: (256,4) and (256,3) both forced scratch spill (rounds 8/9).
// VGPR bucket 129-256 all give 2 waves/SIMD, so register-hoisting is occupancy-free.
__global__ void main_kernel(
    const float* __restrict__ Xt, const float* __restrict__ A,
    const float* __restrict__ xs_ws, const float* __restrict__ c3_ws,
    float* __restrict__ outHess,
    float* __restrict__ gx_ws, float* __restrict__ e_ws, float* __restrict__ s2_ws,
    int Mtot)
{
    const float Q    = 0.22360679774997896f;   // sqrt(5)/SIG
    const float EFC  = 0.0008333333333333334f; // q^4/3
    const float INVQ2 = 20.0f;                 // 1/q^2

    int b = blockIdx.x;
    int chunk = blockIdx.y;
    int tid = threadIdx.x;

    __shared__ float Xt_tile[MT][DPAIR];   // 13.44 KB
    __shared__ float A_tile[MT][DPAIR];    // 13.44 KB
    __shared__ float XJ_lds[MT][64];       // 4 KB
    __shared__ float AJ_lds[MT][64];       // 4 KB
    __shared__ float xs_s[DPAIR];          // 0.84 KB
    __shared__ float c3_s[DPAIR * 3];      // 2.52 KB
    __shared__ float w1_s[MT], g_s[MT], c1_s[MT], ef_s[MT];  // 0.25 KB

    if (tid < DPAIR) xs_s[tid] = xs_ws[b * DPAIR + tid];
    for (int idx = tid; idx < DPAIR * 3; idx += 256) c3_s[idx] = c3_ws[b * DPAIR * 3 + idx];
    __syncthreads();

    // ---- hoist thread-invariant gather operands into registers ----
    // Each thread owns coordinate ac=(atom a, comp c) for the whole m-loop:
    // p20[oo]   = pair index of neighbor oo
    // c3v20[oo] = sign(a,o) * c3[p][c]
    // sxc3      = sum_o xs[p]*c3v   (so xjv = sxc3 - sum_o Xt[m][p]*c3v)
    int ac = tid & 63;
    int a_at = ac < X3 ? ac / 3 : 0;
    int c_at = ac < X3 ? ac - 3 * a_at : 0;
    int p20[20];
    float c3v20[20];
    float sxc3 = 0.f;
    {
        bool live = ac < X3;
        #pragma unroll
        for (int oo = 0; oo < 20; ++oo) {
            int o = oo + (oo >= a_at ? 1 : 0);
            int p = pair_idx(a_at, o);
            float sgn = a_at > o ? 1.f : -1.f;
            float v = live ? sgn * c3_s[p * 3 + c_at] : 0.f;
            p20[oo] = p;
            c3v20[oo] = v;
            sxc3 = fmaf(xs_s[p], v, sxc3);
        }
    }

    int MCH = (Mtot + NCHUNK - 1) / NCHUNK;
    int m0 = chunk * MCH;
    int m1 = min(Mtot, m0 + MCH);

    float acc[4][4];
    #pragma unroll
    for (int i = 0; i < 4; ++i)
        #pragma unroll
        for (int j = 0; j < 4; ++j) acc[i][j] = 0.f;
    float gxp = 0.f, e_acc = 0.f, s2_acc = 0.f;

    int tx = tid >> 4, ty = tid & 15;
    int mtg = tid >> 4, lg = tid & 15;

    for (int t0 = m0; t0 < m1; t0 += MT) {
        // ---- stage Xt/A rows: 16 consecutive m-rows contiguous -> flat float2 copy ----
        {
            int lim2 = ((Mtot - t0) * DPAIR) >> 1;             // float2 available (OOB guard)
            const float2* __restrict__ Xs = (const float2*)(Xt + (size_t)t0 * DPAIR);
            const float2* __restrict__ As = (const float2*)(A  + (size_t)t0 * DPAIR);
            float2* __restrict__ Xd = (float2*)&Xt_tile[0][0];
            float2* __restrict__ Ad = (float2*)&A_tile[0][0];
            #pragma unroll 4
            for (int idx = tid; idx < MT * DPAIR / 2; idx += 256) {
                float2 xv = make_float2(0.f, 0.f), av = make_float2(0.f, 0.f);
                if (idx < lim2) { xv = Xs[idx]; av = As[idx]; }
                Xd[idx] = xv;
                Ad[idx] = av;
            }
        }
        __syncthreads();
        // ---- per-m scalars (16 lanes per m) + private energy/S2 partials ----
        {
            float s2 = 0.f, sxa = 0.f;
            for (int d = lg; d < DPAIR; d += 16) {
                float diff = xs_s[d] - Xt_tile[mtg][d];
                s2 = fmaf(diff, diff, s2);
                sxa = fmaf(diff, A_tile[mtg][d], sxa);
            }
            for (int o = 8; o >= 1; o >>= 1) {
                s2  += __shfl_xor(s2, o, 16);
                sxa += __shfl_xor(sxa, o, 16);
            }
            if (lg == 0) {
                bool valid = (t0 + mtg) < m1;
                float dist = sqrtf(s2);
                float ef = valid ? EFC * expf(-Q * dist) : 0.f;
                float w1 = ef * (1.f + Q * dist) * INVQ2;
                float g  = ef * sxa;
                float c1v = dist > 0.f ? Q * g / dist : 0.f;
                w1_s[mtg] = w1; g_s[mtg] = g; c1_s[mtg] = c1v; ef_s[mtg] = ef;
                e_acc += w1 * sxa;   // private, per-mtg
                s2_acc += g;
            }
        }
        __syncthreads();
        // ---- grad_x partial ----
        if (tid < DPAIR) {
            #pragma unroll
            for (int mt = 0; mt < MT; ++mt)
                gxp += w1_s[mt] * A_tile[mt][tid] + g_s[mt] * Xt_tile[mt][tid];
        }
        // ---- build XJ / AJ using hoisted registers (2 LDS reads per (rr,oo)) ----
        #pragma unroll
        for (int rr = 0; rr < 4; ++rr) {
            int mt = rr * 4 + (tid >> 6);
            const float* __restrict__ Xrow = &Xt_tile[mt][0];
            const float* __restrict__ Arow = &A_tile[mt][0];
            float xjn = 0.f, ajv = 0.f;
            #pragma unroll
            for (int oo = 0; oo < 20; ++oo) {
                xjn = fmaf(Xrow[p20[oo]], c3v20[oo], xjn);
                ajv = fmaf(Arow[p20[oo]], c3v20[oo], ajv);
            }
            float xjv = sxc3 - xjn;
            if (ac < X3) {
                XJ_lds[mt][ac] = xjv;
                AJ_lds[mt][ac] = ajv;
            } else {
                XJ_lds[mt][63] = 0.f;
                AJ_lds[mt][63] = 0.f;
            }
        }
        __syncthreads();
        // ---- 63x63 outer-product accumulation (4x4 per thread over 64x64 padded) ----
        #pragma unroll
        for (int mt = 0; mt < MT; ++mt) {
            const float4* XJ4 = (const float4*)XJ_lds[mt];
            const float4* AJ4 = (const float4*)AJ_lds[mt];
            float c1 = c1_s[mt], ef = ef_s[mt];
            float4 xr = XJ4[tx], ar = AJ4[tx], yc = XJ4[ty], av = AJ4[ty];
            float xx[4] = {xr.x, xr.y, xr.z, xr.w};
            float aa[4] = {ar.x, ar.y, ar.z, ar.w};
            float yy[4] = {yc.x, yc.y, yc.z, yc.w};
            float vv[4] = {av.x, av.y, av.z, av.w};
            float uu[4];
            #pragma unroll
            for (int i = 0; i < 4; ++i) uu[i] = c1 * xx[i] - ef * aa[i];
            #pragma unroll
            for (int j = 0; j < 4; ++j) vv[j] = ef * vv[j];
            #pragma unroll
            for (int i = 0; i < 4; ++i)
                #pragma unroll
                for (int j = 0; j < 4; ++j)
                    acc[i][j] += uu[i] * yy[j] - xx[i] * vv[j];
        }
        __syncthreads();
    }

    // ---- write partials ----
    #pragma unroll
    for (int i = 0; i < 4; ++i) {
        int x = 4 * tx + i;
        if (x >= X3) continue;
        #pragma unroll
        for (int j = 0; j < 4; ++j) {
            int y = 4 * ty + j;
            if (y >= X3) continue;
            atomicAdd(&outHess[((size_t)b * X3 + x) * X3 + y], acc[i][j]);
        }
    }
    if (tid < DPAIR) atomicAdd(&gx_ws[b * DPAIR + tid], gxp);
    if (lg == 0) { atomicAdd(&e_ws[b], e_acc); atomicAdd(&s2_ws[b], s2_acc); }
}

// ---------------- kernel 3: finalize (energy, grad, hessian corrections) ----------------
__global__ void finalize_kernel(
    const float* __restrict__ xs_ws, const float* __restrict__ xs3_ws,
    const float* __restrict__ xs5_ws, const float* __restrict__ dkl_ws,
    const float* __restrict__ c3_ws, const float* __restrict__ gx_ws,
    const float* __restrict__ e_ws, const float* __restrict__ s2_ws,
    float* __restrict__ out, int Bn)
{
    int b = blockIdx.x, tid = threadIdx.x;
    __shared__ float gx_s[DPAIR], xs3_s[DPAIR], xs5_s[DPAIR];
    __shared__ float c3s[DPAIR * 3], dkl_s[DPAIR * 3];
    float S2 = s2_ws[b];
    if (tid < DPAIR) {
        gx_s[tid]  = gx_ws[b * DPAIR + tid] - S2 * xs_ws[b * DPAIR + tid];
        xs3_s[tid] = xs3_ws[b * DPAIR + tid];
        xs5_s[tid] = xs5_ws[b * DPAIR + tid];
    }
    for (int idx = tid; idx < DPAIR * 3; idx += 256) {
        c3s[idx]   = c3_ws[b * DPAIR * 3 + idx];
        dkl_s[idx] = dkl_ws[b * DPAIR * 3 + idx];
    }
    __syncthreads();

    if (tid == 0) out[b] = e_ws[b];   // energy (STD=1, C=0)

    if (tid < X3) {  // grad[b, 3a+c] = sum over incident pairs of sign*gx[p]*c3[p][c]
        int a = tid / 3;
        int c = tid - 3 * a;
        float s = 0.f;
        #pragma unroll
        for (int o = 0; o < N_ATOMS; ++o) {
            if (o == a) continue;
            int p = pair_idx(a, o);
            float sgn = a > o ? 1.f : -1.f;
            s += sgn * gx_s[p] * c3s[p * 3 + c];
        }
        out[Bn + b * X3 + tid] = s;
    }

    float* hess = out + Bn + (size_t)Bn * X3 + (size_t)b * X3 * X3;
    for (int idx = tid; idx < X3 * X3; idx += 256) {
        int x = idx / X3, y = idx - X3 * x;
        int a1 = x / 3, ci = x - 3 * a1;
        int a2 = y / 3, cj = y - 3 * a2;
        float val = hess[idx];
        if (a1 != a2) {
            int p = pair_idx(a1, a2);
            float cc = c3s[p * 3 + ci] * c3s[p * 3 + cj];
            float ht = 3.f * gx_s[p] * xs5_s[p] * dkl_s[p * 3 + ci] * dkl_s[p * 3 + cj]
                       + (ci == cj ? -gx_s[p] * xs3_s[p] : 0.f);
            val += S2 * cc - ht;
        } else {
            int a = a1;
            #pragma unroll
            for (int o = 0; o < N_ATOMS; ++o) {
                if (o == a) continue;
                int p = pair_idx(a, o);
                float cc = c3s[p * 3 + ci] * c3s[p * 3 + cj];
                float ht = 3.f * gx_s[p] * xs5_s[p] * dkl_s[p * 3 + ci] * dkl_s[p * 3 + cj]
                           + (ci == cj ? -gx_s[p] * xs3_s[p] : 0.f);
                val += -S2 * cc + ht;
            }
        }
        hess[idx] = val;
    }
}

extern "C" void kernel_launch(void* const* d_in, const int* in_sizes, int n_in,
                              void* d_out, int out_size, void* d_ws, size_t ws_size,
                              hipStream_t stream) {
    const float* r  = (const float*)d_in[0];
    const float* Xt = (const float*)d_in[1];
    const float* A  = (const float*)d_in[2];
    int Bn   = in_sizes[0] / X3;     // 64
    int Mtot = in_sizes[1] / DPAIR;  // 6000
    float* out = (float*)d_out;

    float* ws     = (float*)d_ws;
    float* gx_ws  = ws;                               // Bn*210 (atomic, zeroed)
    float* e_ws   = gx_ws + (size_t)Bn * DPAIR;       // Bn     (atomic, zeroed)
    float* s2_ws  = e_ws + Bn;                        // Bn     (atomic, zeroed)
    float* xs_ws  = s2_ws + Bn;                       // Bn*210
    float* xs3_ws = xs_ws + (size_t)Bn * DPAIR;       // Bn*210
    float* xs5_ws = xs3_ws + (size_t)Bn * DPAIR;      // Bn*210
    float* dkl_ws = xs5_ws + (size_t)Bn * DPAIR;      // Bn*630
    float* c3_ws  = dkl_ws + (size_t)Bn * DPAIR * 3;  // Bn*630

    hipMemsetAsync(d_out, 0, (size_t)out_size * sizeof(float), stream);
    hipMemsetAsync(ws, 0, ((size_t)Bn * DPAIR + 2 * (size_t)Bn) * sizeof(float), stream);

    geom_kernel<<<Bn, 256, 0, stream>>>(r, xs_ws, xs3_ws, xs5_ws, dkl_ws, c3_ws);

    dim3 grid(Bn, NCHUNK);   // b fastest-varying: co-resident blocks share an m-slab
    main_kernel<<<grid, 256, 0, stream>>>(Xt, A, xs_ws, c3_ws,
        out + Bn + (size_t)Bn * X3, gx_ws, e_ws, s2_ws, Mtot);

    finalize_kernel<<<Bn, 256, 0, stream>>>(xs_ws, xs3_ws, xs5_ws, dkl_ws, c3_ws,
        gx_ws, e_ws, s2_ws, out, Bn);
}

// Round 13
// 844.562 us; speedup vs baseline: 4.5543x; 3.7172x over previous
//
#include <hip/hip_runtime.h>

#define N_ATOMS 21
#define DPAIR 210      // 21*20/2
#define X3 63          // 3*N_ATOMS
#define MT 16          // m-tile per block iteration
#define NCHUNK 8       // m-chunks: 8*64=512 blocks, all resident at 2 blocks/CU

__device__ __forceinline__ int pair_idx(int a, int o) {
    int hi = a > o ? a : o;
    int lo = a > o ? o : a;
    return hi * (hi - 1) / 2 + lo;
}

// ---------------- kernel 1: per-batch pair geometry ----------------
__global__ void geom_kernel(const float* __restrict__ r,
                            float* __restrict__ xs_ws, float* __restrict__ xs3_ws,
                            float* __restrict__ xs5_ws, float* __restrict__ dkl_ws,
                            float* __restrict__ c3_ws) {
    int b = blockIdx.x;
    int tid = threadIdx.x;
    __shared__ float rs[X3];
    if (tid < X3) rs[tid] = r[b * X3 + tid];
    __syncthreads();
    if (tid < DPAIR) {
        int i = (int)((1.0f + sqrtf(1.0f + 8.0f * (float)tid)) * 0.5f);
        while (i * (i - 1) / 2 > tid) --i;
        while ((i + 1) * i / 2 <= tid) ++i;
        int j = tid - i * (i - 1) / 2;   // i > j
        float dx = rs[3 * i + 0] - rs[3 * j + 0];
        float dy = rs[3 * i + 1] - rs[3 * j + 1];
        float dz = rs[3 * i + 2] - rs[3 * j + 2];
        float n2 = dx * dx + dy * dy + dz * dz;
        float inv = 1.0f / sqrtf(n2);      // xs
        float inv2 = inv * inv;
        float x3 = inv2 * inv;
        float x5 = x3 * inv2;
        int gidx = b * DPAIR + tid;
        xs_ws[gidx] = inv;
        xs3_ws[gidx] = x3;
        xs5_ws[gidx] = x5;
        dkl_ws[gidx * 3 + 0] = dx;
        dkl_ws[gidx * 3 + 1] = dy;
        dkl_ws[gidx * 3 + 2] = dz;
        c3_ws[gidx * 3 + 0] = -x3 * dx;   // contrib = -xs^3 * dkl
        c3_ws[gidx * 3 + 1] = -x3 * dy;
        c3_ws[gidx * 3 + 2] = -x3 * dz;
    }
}

// ---------------- kernel 2: main m-loop ----------------
// grid = (B, NCHUNK) -> b fastest-varying so co-resident blocks share an m-slab.
// __launch_bounds__(256) SINGLE-ARG is mandatory: without it hipcc assumes
// 1024-thread blocks and clamps to 64 VGPR -> spill (round 11: 4.1GB scratch
// fetch). (256,4)->64 and (256,3)->84 VGPR also spill (rounds 8/9).
// With (256): 164-168 VGPR measured, no spill; hoist adds ~41 -> ~210, still
// in the 129-256 occupancy bucket (2 waves/SIMD) so register use is free.
__global__ __launch_bounds__(256) void main_kernel(
    const float* __restrict__ Xt, const float* __restrict__ A,
    const float* __restrict__ xs_ws, const float* __restrict__ c3_ws,
    float* __restrict__ outHess,
    float* __restrict__ gx_ws, float* __restrict__ e_ws, float* __restrict__ s2_ws,
    int Mtot)
{
    const float Q    = 0.22360679774997896f;   // sqrt(5)/SIG
    const float EFC  = 0.0008333333333333334f; // q^4/3
    const float INVQ2 = 20.0f;                 // 1/q^2

    int b = blockIdx.x;
    int chunk = blockIdx.y;
    int tid = threadIdx.x;

    __shared__ float Xt_tile[MT][DPAIR];   // 13.44 KB
    __shared__ float A_tile[MT][DPAIR];    // 13.44 KB
    __shared__ float XJ_lds[MT][64];       // 4 KB
    __shared__ float AJ_lds[MT][64];       // 4 KB
    __shared__ float xs_s[DPAIR];          // 0.84 KB
    __shared__ float c3_s[DPAIR * 3];      // 2.52 KB
    __shared__ float w1_s[MT], g_s[MT], c1_s[MT], ef_s[MT];  // 0.25 KB

    if (tid < DPAIR) xs_s[tid] = xs_ws[b * DPAIR + tid];
    for (int idx = tid; idx < DPAIR * 3; idx += 256) c3_s[idx] = c3_ws[b * DPAIR * 3 + idx];
    __syncthreads();

    // ---- hoist thread-invariant gather operands into registers ----
    // Each thread owns coordinate ac=(atom a, comp c) for the whole m-loop:
    // p20[oo]   = pair index of neighbor oo
    // c3v20[oo] = sign(a,o) * c3[p][c]
    // sxc3      = sum_o xs[p]*c3v   (so xjv = sxc3 - sum_o Xt[m][p]*c3v)
    int ac = tid & 63;
    int a_at = ac < X3 ? ac / 3 : 0;
    int c_at = ac < X3 ? ac - 3 * a_at : 0;
    int p20[20];
    float c3v20[20];
    float sxc3 = 0.f;
    {
        bool live = ac < X3;
        #pragma unroll
        for (int oo = 0; oo < 20; ++oo) {
            int o = oo + (oo >= a_at ? 1 : 0);
            int p = pair_idx(a_at, o);
            float sgn = a_at > o ? 1.f : -1.f;
            float v = live ? sgn * c3_s[p * 3 + c_at] : 0.f;
            p20[oo] = p;
            c3v20[oo] = v;
            sxc3 = fmaf(xs_s[p], v, sxc3);
        }
    }

    int MCH = (Mtot + NCHUNK - 1) / NCHUNK;
    int m0 = chunk * MCH;
    int m1 = min(Mtot, m0 + MCH);

    float acc[4][4];
    #pragma unroll
    for (int i = 0; i < 4; ++i)
        #pragma unroll
        for (int j = 0; j < 4; ++j) acc[i][j] = 0.f;
    float gxp = 0.f, e_acc = 0.f, s2_acc = 0.f;

    int tx = tid >> 4, ty = tid & 15;
    int mtg = tid >> 4, lg = tid & 15;

    for (int t0 = m0; t0 < m1; t0 += MT) {
        // ---- stage Xt/A rows: 16 consecutive m-rows contiguous -> flat float2 copy ----
        {
            int lim2 = ((Mtot - t0) * DPAIR) >> 1;             // float2 available (OOB guard)
            const float2* __restrict__ Xs = (const float2*)(Xt + (size_t)t0 * DPAIR);
            const float2* __restrict__ As = (const float2*)(A  + (size_t)t0 * DPAIR);
            float2* __restrict__ Xd = (float2*)&Xt_tile[0][0];
            float2* __restrict__ Ad = (float2*)&A_tile[0][0];
            #pragma unroll 4
            for (int idx = tid; idx < MT * DPAIR / 2; idx += 256) {
                float2 xv = make_float2(0.f, 0.f), av = make_float2(0.f, 0.f);
                if (idx < lim2) { xv = Xs[idx]; av = As[idx]; }
                Xd[idx] = xv;
                Ad[idx] = av;
            }
        }
        __syncthreads();
        // ---- per-m scalars (16 lanes per m) + private energy/S2 partials ----
        {
            float s2 = 0.f, sxa = 0.f;
            for (int d = lg; d < DPAIR; d += 16) {
                float diff = xs_s[d] - Xt_tile[mtg][d];
                s2 = fmaf(diff, diff, s2);
                sxa = fmaf(diff, A_tile[mtg][d], sxa);
            }
            for (int o = 8; o >= 1; o >>= 1) {
                s2  += __shfl_xor(s2, o, 16);
                sxa += __shfl_xor(sxa, o, 16);
            }
            if (lg == 0) {
                bool valid = (t0 + mtg) < m1;
                float dist = sqrtf(s2);
                float ef = valid ? EFC * expf(-Q * dist) : 0.f;
                float w1 = ef * (1.f + Q * dist) * INVQ2;
                float g  = ef * sxa;
                float c1v = dist > 0.f ? Q * g / dist : 0.f;
                w1_s[mtg] = w1; g_s[mtg] = g; c1_s[mtg] = c1v; ef_s[mtg] = ef;
                e_acc += w1 * sxa;   // private, per-mtg
                s2_acc += g;
            }
        }
        __syncthreads();
        // ---- grad_x partial ----
        if (tid < DPAIR) {
            #pragma unroll
            for (int mt = 0; mt < MT; ++mt)
                gxp += w1_s[mt] * A_tile[mt][tid] + g_s[mt] * Xt_tile[mt][tid];
        }
        // ---- build XJ / AJ using hoisted registers (2 LDS reads per (rr,oo)) ----
        #pragma unroll
        for (int rr = 0; rr < 4; ++rr) {
            int mt = rr * 4 + (tid >> 6);
            const float* __restrict__ Xrow = &Xt_tile[mt][0];
            const float* __restrict__ Arow = &A_tile[mt][0];
            float xjn = 0.f, ajv = 0.f;
            #pragma unroll
            for (int oo = 0; oo < 20; ++oo) {
                xjn = fmaf(Xrow[p20[oo]], c3v20[oo], xjn);
                ajv = fmaf(Arow[p20[oo]], c3v20[oo], ajv);
            }
            float xjv = sxc3 - xjn;
            if (ac < X3) {
                XJ_lds[mt][ac] = xjv;
                AJ_lds[mt][ac] = ajv;
            } else {
                XJ_lds[mt][63] = 0.f;
                AJ_lds[mt][63] = 0.f;
            }
        }
        __syncthreads();
        // ---- 63x63 outer-product accumulation (4x4 per thread over 64x64 padded) ----
        #pragma unroll
        for (int mt = 0; mt < MT; ++mt) {
            const float4* XJ4 = (const float4*)XJ_lds[mt];
            const float4* AJ4 = (const float4*)AJ_lds[mt];
            float c1 = c1_s[mt], ef = ef_s[mt];
            float4 xr = XJ4[tx], ar = AJ4[tx], yc = XJ4[ty], av = AJ4[ty];
            float xx[4] = {xr.x, xr.y, xr.z, xr.w};
            float aa[4] = {ar.x, ar.y, ar.z, ar.w};
            float yy[4] = {yc.x, yc.y, yc.z, yc.w};
            float vv[4] = {av.x, av.y, av.z, av.w};
            float uu[4];
            #pragma unroll
            for (int i = 0; i < 4; ++i) uu[i] = c1 * xx[i] - ef * aa[i];
            #pragma unroll
            for (int j = 0; j < 4; ++j) vv[j] = ef * vv[j];
            #pragma unroll
            for (int i = 0; i < 4; ++i)
                #pragma unroll
                for (int j = 0; j < 4; ++j)
                    acc[i][j] += uu[i] * yy[j] - xx[i] * vv[j];
        }
        __syncthreads();
    }

    // ---- write partials ----
    #pragma unroll
    for (int i = 0; i < 4; ++i) {
        int x = 4 * tx + i;
        if (x >= X3) continue;
        #pragma unroll
        for (int j = 0; j < 4; ++j) {
            int y = 4 * ty + j;
            if (y >= X3) continue;
            atomicAdd(&outHess[((size_t)b * X3 + x) * X3 + y], acc[i][j]);
        }
    }
    if (tid < DPAIR) atomicAdd(&gx_ws[b * DPAIR + tid], gxp);
    if (lg == 0) { atomicAdd(&e_ws[b], e_acc); atomicAdd(&s2_ws[b], s2_acc); }
}

// ---------------- kernel 3: finalize (energy, grad, hessian corrections) ----------------
__global__ __launch_bounds__(256) void finalize_kernel(
    const float* __restrict__ xs_ws, const float* __restrict__ xs3_ws,
    const float* __restrict__ xs5_ws, const float* __restrict__ dkl_ws,
    const float* __restrict__ c3_ws, const float* __restrict__ gx_ws,
    const float* __restrict__ e_ws, const float* __restrict__ s2_ws,
    float* __restrict__ out, int Bn)
{
    int b = blockIdx.x, tid = threadIdx.x;
    __shared__ float gx_s[DPAIR], xs3_s[DPAIR], xs5_s[DPAIR];
    __shared__ float c3s[DPAIR * 3], dkl_s[DPAIR * 3];
    float S2 = s2_ws[b];
    if (tid < DPAIR) {
        gx_s[tid]  = gx_ws[b * DPAIR + tid] - S2 * xs_ws[b * DPAIR + tid];
        xs3_s[tid] = xs3_ws[b * DPAIR + tid];
        xs5_s[tid] = xs5_ws[b * DPAIR + tid];
    }
    for (int idx = tid; idx < DPAIR * 3; idx += 256) {
        c3s[idx]   = c3_ws[b * DPAIR * 3 + idx];
        dkl_s[idx] = dkl_ws[b * DPAIR * 3 + idx];
    }
    __syncthreads();

    if (tid == 0) out[b] = e_ws[b];   // energy (STD=1, C=0)

    if (tid < X3) {  // grad[b, 3a+c] = sum over incident pairs of sign*gx[p]*c3[p][c]
        int a = tid / 3;
        int c = tid - 3 * a;
        float s = 0.f;
        #pragma unroll
        for (int o = 0; o < N_ATOMS; ++o) {
            if (o == a) continue;
            int p = pair_idx(a, o);
            float sgn = a > o ? 1.f : -1.f;
            s += sgn * gx_s[p] * c3s[p * 3 + c];
        }
        out[Bn + b * X3 + tid] = s;
    }

    float* hess = out + Bn + (size_t)Bn * X3 + (size_t)b * X3 * X3;
    for (int idx = tid; idx < X3 * X3; idx += 256) {
        int x = idx / X3, y = idx - X3 * x;
        int a1 = x / 3, ci = x - 3 * a1;
        int a2 = y / 3, cj = y - 3 * a2;
        float val = hess[idx];
        if (a1 != a2) {
            int p = pair_idx(a1, a2);
            float cc = c3s[p * 3 + ci] * c3s[p * 3 + cj];
            float ht = 3.f * gx_s[p] * xs5_s[p] * dkl_s[p * 3 + ci] * dkl_s[p * 3 + cj]
                       + (ci == cj ? -gx_s[p] * xs3_s[p] : 0.f);
            val += S2 * cc - ht;
        } else {
            int a = a1;
            #pragma unroll
            for (int o = 0; o < N_ATOMS; ++o) {
                if (o == a) continue;
                int p = pair_idx(a, o);
                float cc = c3s[p * 3 + ci] * c3s[p * 3 + cj];
                float ht = 3.f * gx_s[p] * xs5_s[p] * dkl_s[p * 3 + ci] * dkl_s[p * 3 + cj]
                           + (ci == cj ? -gx_s[p] * xs3_s[p] : 0.f);
                val += -S2 * cc + ht;
            }
        }
        hess[idx] = val;
    }
}

extern "C" void kernel_launch(void* const* d_in, const int* in_sizes, int n_in,
                              void* d_out, int out_size, void* d_ws, size_t ws_size,
                              hipStream_t stream) {
    const float* r  = (const float*)d_in[0];
    const float* Xt = (const float*)d_in[1];
    const float* A  = (const float*)d_in[2];
    int Bn   = in_sizes[0] / X3;     // 64
    int Mtot = in_sizes[1] / DPAIR;  // 6000
    float* out = (float*)d_out;

    float* ws     = (float*)d_ws;
    float* gx_ws  = ws;                               // Bn*210 (atomic, zeroed)
    float* e_ws   = gx_ws + (size_t)Bn * DPAIR;       // Bn     (atomic, zeroed)
    float* s2_ws  = e_ws + Bn;                        // Bn     (atomic, zeroed)
    float* xs_ws  = s2_ws + Bn;                       // Bn*210
    float* xs3_ws = xs_ws + (size_t)Bn * DPAIR;       // Bn*210
    float* xs5_ws = xs3_ws + (size_t)Bn * DPAIR;      // Bn*210
    float* dkl_ws = xs5_ws + (size_t)Bn * DPAIR;      // Bn*630
    float* c3_ws  = dkl_ws + (size_t)Bn * DPAIR * 3;  // Bn*630

    hipMemsetAsync(d_out, 0, (size_t)out_size * sizeof(float), stream);
    hipMemsetAsync(ws, 0, ((size_t)Bn * DPAIR + 2 * (size_t)Bn) * sizeof(float), stream);

    geom_kernel<<<Bn, 256, 0, stream>>>(r, xs_ws, xs3_ws, xs5_ws, dkl_ws, c3_ws);

    dim3 grid(Bn, NCHUNK);   // b fastest-varying: co-resident blocks share an m-slab
    main_kernel<<<grid, 256, 0, stream>>>(Xt, A, xs_ws, c3_ws,
        out + Bn + (size_t)Bn * X3, gx_ws, e_ws, s2_ws, Mtot);

    finalize_kernel<<<Bn, 256, 0, stream>>>(xs_ws, xs3_ws, xs5_ws, dkl_ws, c3_ws,
        gx_ws, e_ws, s2_ws, out, Bn);
}

// Round 15
// 523.932 us; speedup vs baseline: 7.3414x; 1.6120x over previous
//
#include <hip/hip_runtime.h>

#define N_ATOMS 21
#define DPAIR 210      // 21*20/2
#define X3 63          // 3*N_ATOMS
#define MT 32          // m-tile per block iteration (r13 verified base had 16)
#define NCHUNK 8       // m-chunks: 8*64=512 blocks, all resident at 2 blocks/CU

__device__ __forceinline__ int pair_idx(int a, int o) {
    int hi = a > o ? a : o;
    int lo = a > o ? o : a;
    return hi * (hi - 1) / 2 + lo;
}

// ---------------- kernel 1: per-batch pair geometry ----------------
__global__ void geom_kernel(const float* __restrict__ r,
                            float* __restrict__ xs_ws, float* __restrict__ xs3_ws,
                            float* __restrict__ xs5_ws, float* __restrict__ dkl_ws,
                            float* __restrict__ c3_ws) {
    int b = blockIdx.x;
    int tid = threadIdx.x;
    __shared__ float rs[X3];
    if (tid < X3) rs[tid] = r[b * X3 + tid];
    __syncthreads();
    if (tid < DPAIR) {
        int i = (int)((1.0f + sqrtf(1.0f + 8.0f * (float)tid)) * 0.5f);
        while (i * (i - 1) / 2 > tid) --i;
        while ((i + 1) * i / 2 <= tid) ++i;
        int j = tid - i * (i - 1) / 2;   // i > j
        float dx = rs[3 * i + 0] - rs[3 * j + 0];
        float dy = rs[3 * i + 1] - rs[3 * j + 1];
        float dz = rs[3 * i + 2] - rs[3 * j + 2];
        float n2 = dx * dx + dy * dy + dz * dz;
        float inv = 1.0f / sqrtf(n2);      // xs
        float inv2 = inv * inv;
        float x3 = inv2 * inv;
        float x5 = x3 * inv2;
        int gidx = b * DPAIR + tid;
        xs_ws[gidx] = inv;
        xs3_ws[gidx] = x3;
        xs5_ws[gidx] = x5;
        dkl_ws[gidx * 3 + 0] = dx;
        dkl_ws[gidx * 3 + 1] = dy;
        dkl_ws[gidx * 3 + 2] = dz;
        c3_ws[gidx * 3 + 0] = -x3 * dx;   // contrib = -xs^3 * dkl
        c3_ws[gidx * 3 + 1] = -x3 * dy;
        c3_ws[gidx * 3 + 2] = -x3 * dz;
    }
}

// ---------------- kernel 2: main m-loop ----------------
// r13-verified 256-thread structure (844us total, passed post-timing checks);
// only change: MT 16->32 to halve barriers-per-m. LDS ~74KB -> 2 blocks/CU
// (148<160KB), same 8 waves/CU residency as r13 (VGPR-capped).
// __launch_bounds__(256) SINGLE-ARG is mandatory: no-arg -> 64 VGPR clamp/spill
// (r11), (256,4)/(256,3) -> spill (r8/r9). r14's 512-thread variant failed the
// post-timing determinism tripwire — do not revisit without a root cause.
__global__ __launch_bounds__(256) void main_kernel(
    const float* __restrict__ Xt, const float* __restrict__ A,
    const float* __restrict__ xs_ws, const float* __restrict__ c3_ws,
    float* __restrict__ outHess,
    float* __restrict__ gx_ws, float* __restrict__ e_ws, float* __restrict__ s2_ws,
    int Mtot)
{
    const float Q    = 0.22360679774997896f;   // sqrt(5)/SIG
    const float EFC  = 0.0008333333333333334f; // q^4/3
    const float INVQ2 = 20.0f;                 // 1/q^2

    int b = blockIdx.x;
    int chunk = blockIdx.y;
    int tid = threadIdx.x;

    __shared__ float Xt_tile[MT][DPAIR];   // 26.88 KB
    __shared__ float A_tile[MT][DPAIR];    // 26.88 KB
    __shared__ float XJ_lds[MT][64];       // 8 KB
    __shared__ float AJ_lds[MT][64];       // 8 KB
    __shared__ float xs_s[DPAIR];          // 0.84 KB
    __shared__ float c3_s[DPAIR * 3];      // 2.52 KB
    __shared__ float w1_s[MT], g_s[MT], c1_s[MT], ef_s[MT];  // 0.5 KB
    // total ~73.6 KB -> 2 blocks/CU

    if (tid < DPAIR) xs_s[tid] = xs_ws[b * DPAIR + tid];
    for (int idx = tid; idx < DPAIR * 3; idx += 256) c3_s[idx] = c3_ws[b * DPAIR * 3 + idx];
    __syncthreads();

    // ---- hoist thread-invariant gather operands into registers (r13, verified) ----
    int ac = tid & 63;
    int a_at = ac < X3 ? ac / 3 : 0;
    int c_at = ac < X3 ? ac - 3 * a_at : 0;
    int p20[20];
    float c3v20[20];
    float sxc3 = 0.f;
    {
        bool live = ac < X3;
        #pragma unroll
        for (int oo = 0; oo < 20; ++oo) {
            int o = oo + (oo >= a_at ? 1 : 0);
            int p = pair_idx(a_at, o);
            float sgn = a_at > o ? 1.f : -1.f;
            float v = live ? sgn * c3_s[p * 3 + c_at] : 0.f;
            p20[oo] = p;
            c3v20[oo] = v;
            sxc3 = fmaf(xs_s[p], v, sxc3);
        }
    }

    int MCH = (Mtot + NCHUNK - 1) / NCHUNK;
    int m0 = chunk * MCH;
    int m1 = min(Mtot, m0 + MCH);

    float acc[4][4];
    #pragma unroll
    for (int i = 0; i < 4; ++i)
        #pragma unroll
        for (int j = 0; j < 4; ++j) acc[i][j] = 0.f;
    float gxp = 0.f, e_acc = 0.f, s2_acc = 0.f;

    int tx = tid >> 4, ty = tid & 15;
    int mtg = tid >> 3, lg = tid & 7;   // scalar phase: 8 lanes per m, 32 m's

    for (int t0 = m0; t0 < m1; t0 += MT) {
        // ---- stage Xt/A rows: 32 contiguous rows -> flat float2 copy ----
        {
            int lim2 = ((Mtot - t0) * DPAIR) >> 1;             // OOB guard vs Mtot
            const float2* __restrict__ Xs = (const float2*)(Xt + (size_t)t0 * DPAIR);
            const float2* __restrict__ As = (const float2*)(A  + (size_t)t0 * DPAIR);
            float2* __restrict__ Xd = (float2*)&Xt_tile[0][0];
            float2* __restrict__ Ad = (float2*)&A_tile[0][0];
            #pragma unroll 4
            for (int idx = tid; idx < MT * DPAIR / 2; idx += 256) {
                float2 xv = make_float2(0.f, 0.f), av = make_float2(0.f, 0.f);
                if (idx < lim2) { xv = Xs[idx]; av = As[idx]; }
                Xd[idx] = xv;
                Ad[idx] = av;
            }
        }
        __syncthreads();
        // ---- per-m scalars (8 lanes per m) + private energy/S2 partials ----
        {
            float s2 = 0.f, sxa = 0.f;
            for (int d = lg; d < DPAIR; d += 8) {
                float diff = xs_s[d] - Xt_tile[mtg][d];
                s2 = fmaf(diff, diff, s2);
                sxa = fmaf(diff, A_tile[mtg][d], sxa);
            }
            #pragma unroll
            for (int o = 4; o >= 1; o >>= 1) {
                s2  += __shfl_xor(s2, o, 8);
                sxa += __shfl_xor(sxa, o, 8);
            }
            if (lg == 0) {
                bool valid = (t0 + mtg) < m1;
                float dist = sqrtf(s2);
                float ef = valid ? EFC * expf(-Q * dist) : 0.f;
                float w1 = ef * (1.f + Q * dist) * INVQ2;
                float g  = ef * sxa;
                float c1v = dist > 0.f ? Q * g / dist : 0.f;
                w1_s[mtg] = w1; g_s[mtg] = g; c1_s[mtg] = c1v; ef_s[mtg] = ef;
                e_acc += w1 * sxa;   // private, per-mtg
                s2_acc += g;
            }
        }
        __syncthreads();
        // ---- grad_x partial ----
        if (tid < DPAIR) {
            #pragma unroll 8
            for (int mt = 0; mt < MT; ++mt)
                gxp += w1_s[mt] * A_tile[mt][tid] + g_s[mt] * Xt_tile[mt][tid];
        }
        // ---- build XJ / AJ using hoisted registers ----
        #pragma unroll 4
        for (int rr = 0; rr < 8; ++rr) {
            int mt = rr * 4 + (tid >> 6);
            const float* __restrict__ Xrow = &Xt_tile[mt][0];
            const float* __restrict__ Arow = &A_tile[mt][0];
            float xjn = 0.f, ajv = 0.f;
            #pragma unroll
            for (int oo = 0; oo < 20; ++oo) {
                xjn = fmaf(Xrow[p20[oo]], c3v20[oo], xjn);
                ajv = fmaf(Arow[p20[oo]], c3v20[oo], ajv);
            }
            float xjv = sxc3 - xjn;
            if (ac < X3) {
                XJ_lds[mt][ac] = xjv;
                AJ_lds[mt][ac] = ajv;
            } else {
                XJ_lds[mt][63] = 0.f;
                AJ_lds[mt][63] = 0.f;
            }
        }
        __syncthreads();
        // ---- 63x63 outer-product accumulation (4x4 per thread over 64x64 padded) ----
        #pragma unroll 8
        for (int mt = 0; mt < MT; ++mt) {
            const float4* XJ4 = (const float4*)XJ_lds[mt];
            const float4* AJ4 = (const float4*)AJ_lds[mt];
            float c1 = c1_s[mt], ef = ef_s[mt];
            float4 xr = XJ4[tx], ar = AJ4[tx], yc = XJ4[ty], av = AJ4[ty];
            float xx[4] = {xr.x, xr.y, xr.z, xr.w};
            float aa[4] = {ar.x, ar.y, ar.z, ar.w};
            float yy[4] = {yc.x, yc.y, yc.z, yc.w};
            float vv[4] = {av.x, av.y, av.z, av.w};
            float uu[4];
            #pragma unroll
            for (int i = 0; i < 4; ++i) uu[i] = c1 * xx[i] - ef * aa[i];
            #pragma unroll
            for (int j = 0; j < 4; ++j) vv[j] = ef * vv[j];
            #pragma unroll
            for (int i = 0; i < 4; ++i)
                #pragma unroll
                for (int j = 0; j < 4; ++j)
                    acc[i][j] += uu[i] * yy[j] - xx[i] * vv[j];
        }
        __syncthreads();
    }

    // ---- write partials ----
    #pragma unroll
    for (int i = 0; i < 4; ++i) {
        int x = 4 * tx + i;
        if (x >= X3) continue;
        #pragma unroll
        for (int j = 0; j < 4; ++j) {
            int y = 4 * ty + j;
            if (y >= X3) continue;
            atomicAdd(&outHess[((size_t)b * X3 + x) * X3 + y], acc[i][j]);
        }
    }
    if (tid < DPAIR) atomicAdd(&gx_ws[b * DPAIR + tid], gxp);
    if (lg == 0) { atomicAdd(&e_ws[b], e_acc); atomicAdd(&s2_ws[b], s2_acc); }
}

// ---------------- kernel 3: finalize (energy, grad, hessian corrections) ----------------
__global__ __launch_bounds__(256) void finalize_kernel(
    const float* __restrict__ xs_ws, const float* __restrict__ xs3_ws,
    const float* __restrict__ xs5_ws, const float* __restrict__ dkl_ws,
    const float* __restrict__ c3_ws, const float* __restrict__ gx_ws,
    const float* __restrict__ e_ws, const float* __restrict__ s2_ws,
    float* __restrict__ out, int Bn)
{
    int b = blockIdx.x, tid = threadIdx.x;
    __shared__ float gx_s[DPAIR], xs3_s[DPAIR], xs5_s[DPAIR];
    __shared__ float c3s[DPAIR * 3], dkl_s[DPAIR * 3];
    float S2 = s2_ws[b];
    if (tid < DPAIR) {
        gx_s[tid]  = gx_ws[b * DPAIR + tid] - S2 * xs_ws[b * DPAIR + tid];
        xs3_s[tid] = xs3_ws[b * DPAIR + tid];
        xs5_s[tid] = xs5_ws[b * DPAIR + tid];
    }
    for (int idx = tid; idx < DPAIR * 3; idx += 256) {
        c3s[idx]   = c3_ws[b * DPAIR * 3 + idx];
        dkl_s[idx] = dkl_ws[b * DPAIR * 3 + idx];
    }
    __syncthreads();

    if (tid == 0) out[b] = e_ws[b];   // energy (STD=1, C=0)

    if (tid < X3) {
        int a = tid / 3;
        int c = tid - 3 * a;
        float s = 0.f;
        #pragma unroll
        for (int o = 0; o < N_ATOMS; ++o) {
            if (o == a) continue;
            int p = pair_idx(a, o);
            float sgn = a > o ? 1.f : -1.f;
            s += sgn * gx_s[p] * c3s[p * 3 + c];
        }
        out[Bn + b * X3 + tid] = s;
    }

    float* hess = out + Bn + (size_t)Bn * X3 + (size_t)b * X3 * X3;
    for (int idx = tid; idx < X3 * X3; idx += 256) {
        int x = idx / X3, y = idx - X3 * x;
        int a1 = x / 3, ci = x - 3 * a1;
        int a2 = y / 3, cj = y - 3 * a2;
        float val = hess[idx];
        if (a1 != a2) {
            int p = pair_idx(a1, a2);
            float cc = c3s[p * 3 + ci] * c3s[p * 3 + cj];
            float ht = 3.f * gx_s[p] * xs5_s[p] * dkl_s[p * 3 + ci] * dkl_s[p * 3 + cj]
                       + (ci == cj ? -gx_s[p] * xs3_s[p] : 0.f);
            val += S2 * cc - ht;
        } else {
            int a = a1;
            #pragma unroll
            for (int o = 0; o < N_ATOMS; ++o) {
                if (o == a) continue;
                int p = pair_idx(a, o);
                float cc = c3s[p * 3 + ci] * c3s[p * 3 + cj];
                float ht = 3.f * gx_s[p] * xs5_s[p] * dkl_s[p * 3 + ci] * dkl_s[p * 3 + cj]
                           + (ci == cj ? -gx_s[p] * xs3_s[p] : 0.f);
                val += -S2 * cc + ht;
            }
        }
        hess[idx] = val;
    }
}

extern "C" void kernel_launch(void* const* d_in, const int* in_sizes, int n_in,
                              void* d_out, int out_size, void* d_ws, size_t ws_size,
                              hipStream_t stream) {
    const float* r  = (const float*)d_in[0];
    const float* Xt = (const float*)d_in[1];
    const float* A  = (const float*)d_in[2];
    int Bn   = in_sizes[0] / X3;     // 64
    int Mtot = in_sizes[1] / DPAIR;  // 6000
    float* out = (float*)d_out;

    float* ws     = (float*)d_ws;
    float* gx_ws  = ws;                               // Bn*210 (atomic, zeroed)
    float* e_ws   = gx_ws + (size_t)Bn * DPAIR;       // Bn     (atomic, zeroed)
    float* s2_ws  = e_ws + Bn;                        // Bn     (atomic, zeroed)
    float* xs_ws  = s2_ws + Bn;                       // Bn*210
    float* xs3_ws = xs_ws + (size_t)Bn * DPAIR;       // Bn*210
    float* xs5_ws = xs3_ws + (size_t)Bn * DPAIR;      // Bn*210
    float* dkl_ws = xs5_ws + (size_t)Bn * DPAIR;      // Bn*630
    float* c3_ws  = dkl_ws + (size_t)Bn * DPAIR * 3;  // Bn*630

    hipMemsetAsync(d_out, 0, (size_t)out_size * sizeof(float), stream);
    hipMemsetAsync(ws, 0, ((size_t)Bn * DPAIR + 2 * (size_t)Bn) * sizeof(float), stream);

    geom_kernel<<<Bn, 256, 0, stream>>>(r, xs_ws, xs3_ws, xs5_ws, dkl_ws, c3_ws);

    dim3 grid(Bn, NCHUNK);   // b fastest-varying: co-resident blocks share an m-slab
    main_kernel<<<grid, 256, 0, stream>>>(Xt, A, xs_ws, c3_ws,
        out + Bn + (size_t)Bn * X3, gx_ws, e_ws, s2_ws, Mtot);

    finalize_kernel<<<Bn, 256, 0, stream>>>(xs_ws, xs3_ws, xs5_ws, dkl_ws, c3_ws,
        gx_ws, e_ws, s2_ws, out, Bn);
}